// Round 2
// baseline (1305.250 us; speedup 1.0000x reference)
//
#include <hip/hip_runtime.h>

// Problem constants (from reference): B=2, C=32, N_IN=2^20, N_OUT=2^21.
constexpr int kNIn  = 1 << 20;
constexpr int kNOut = 1 << 21;
constexpr int kSlices = 2 * 32;              // B * C
constexpr int kVec = 4;                      // float4 per thread
constexpr int kVecPerSlice = kNOut / kVec;   // 2^19
constexpr int kVecShift = 19;                // log2(kVecPerSlice)
constexpr long long kTotalVec = (long long)kSlices * kVecPerSlice; // 33,554,432

typedef float  v4f __attribute__((ext_vector_type(4)));  // native vec for nt-store
typedef int    v4i __attribute__((ext_vector_type(4)));

__global__ __launch_bounds__(256)
void SampleParticles_36653250904489_kernel(const float* __restrict__ in,
                                           const int*   __restrict__ pidx,
                                           float*       __restrict__ out) {
    const int tid = blockIdx.x * blockDim.x + threadIdx.x;   // < 2^25, fits int
    const int vec_i = tid & (kVecPerSlice - 1);
    const int slice = tid >> kVecShift;                      // b*C + c

    // Index load: coalesced int4; identical across the 64 slices -> L2/L3 hit
    // on all but the first slice touching each line.
    const v4i p = ((const v4i* __restrict__)pidx)[vec_i];

    // Gather within this slice's 4 MiB window (fits one XCD L2).
    const float* __restrict__ base = in + (size_t)slice * kNIn;
    v4f v;
    v.x = base[p.x];
    v.y = base[p.y];
    v.z = base[p.z];
    v.w = base[p.w];

    // Streaming store: never re-read; nt keeps the 512 MiB write stream from
    // evicting the gather working set in L2.
    v4f* dst = (v4f*)(out + (size_t)slice * kNOut) + vec_i;
    __builtin_nontemporal_store(v, dst);
}

extern "C" void kernel_launch(void* const* d_in, const int* in_sizes, int n_in,
                              void* d_out, int out_size, void* d_ws, size_t ws_size,
                              hipStream_t stream) {
    const float* in   = (const float*)d_in[0];
    const int*   pidx = (const int*)d_in[1];
    float*       out  = (float*)d_out;

    const int threads = 256;
    const int blocks  = (int)(kTotalVec / threads);   // 131072, exact (no tail)
    SampleParticles_36653250904489_kernel<<<blocks, threads, 0, stream>>>(in, pidx, out);
}